// Round 3
// 224.611 us; speedup vs baseline: 1.0175x; 1.0175x over previous
//
#include <hip/hip_runtime.h>

typedef unsigned short u16;
typedef unsigned int   u32;
typedef u16  u16x8 __attribute__((ext_vector_type(8)));
typedef u16  u16x4 __attribute__((ext_vector_type(4)));
typedef float f32x4 __attribute__((ext_vector_type(4)));
typedef __bf16 bf16x8 __attribute__((ext_vector_type(8)));

#define SEQ   512
#define DIM   512
#define DHEAD 64
#define M_ROWS 16384   // 4*8*512

#define AS1 __attribute__((address_space(1)))
#define AS3 __attribute__((address_space(3)))
// async global->LDS, 16B per lane, LDS dest = wave-uniform base + lane*16
#define GLL16(gp, lp) __builtin_amdgcn_global_load_lds((const AS1 void*)(gp), (AS3 void*)(lp), 16, 0, 0)

__device__ __forceinline__ u16 f2b(float f) {
  u32 x = __builtin_bit_cast(u32, f);
  return (u16)((x + 0x7fffu + ((x >> 16) & 1u)) >> 16);
}

// ---------------------------------------------------------------------------
// Kernel 0: prep = convert inputs fp32->bf16 (blocks 0..8191) + weight
// transpose fp32 [K,N] -> bf16 [N,K] (blocks 8192..9215). One launch.
// ---------------------------------------------------------------------------
__global__ __launch_bounds__(256) void prep(const float* __restrict__ q,
                                            const float* __restrict__ kv,
                                            const float* __restrict__ Wq,
                                            const float* __restrict__ Wk,
                                            const float* __restrict__ Wv,
                                            const float* __restrict__ Wo,
                                            u16* __restrict__ qb,
                                            u16* __restrict__ kvb,
                                            u16* __restrict__ wout) {
  __shared__ float tile[32][33];
  const int bid = blockIdx.x;
  if (bid < 8192) {
    const float* src = (bid >= 4096) ? kv : q;
    u16* dst = (bid >= 4096) ? kvb : qb;
    size_t i = ((size_t)(bid & 4095) * 256 + threadIdx.x) * 8;
    float4 a = *reinterpret_cast<const float4*>(&src[i]);
    float4 b = *reinterpret_cast<const float4*>(&src[i + 4]);
    u16x8 o;
    o[0] = f2b(a.x); o[1] = f2b(a.y); o[2] = f2b(a.z); o[3] = f2b(a.w);
    o[4] = f2b(b.x); o[5] = f2b(b.y); o[6] = f2b(b.z); o[7] = f2b(b.w);
    *reinterpret_cast<u16x8*>(&dst[i]) = o;
  } else {
    const int rem = bid - 8192;          // 0..1023
    const int z = rem >> 8;              // weight index 0..3
    const int t = rem & 255;
    const int n0 = (t & 15) * 32;
    const int k0 = (t >> 4) * 32;
    const int tid = threadIdx.x;
    const int tx = tid & 31, ty = tid >> 5;
    const float* W = (z == 0) ? Wq : (z == 1) ? Wk : (z == 2) ? Wv : Wo;
#pragma unroll
    for (int i = 0; i < 4; i++) {
      int r = ty + i * 8;
      tile[r][tx] = W[(k0 + r) * DIM + n0 + tx];
    }
    __syncthreads();
    u16* o = wout + (size_t)z * DIM * DIM;
#pragma unroll
    for (int i = 0; i < 4; i++) {
      int r = ty + i * 8;
      o[(n0 + r) * DIM + k0 + tx] = f2b(tile[tx][r]);
    }
  }
}

// ---------------------------------------------------------------------------
// Kernel 1: fused Q/K/V^T projection GEMM, all-bf16, GLL16 staging.
// 256x128 tile, BK=32, 4 waves in 2x2, each wave 128x64 (8x4 MFMA 16x16x32).
//  z=0: Qb[M,512] = Qin_b @ Wq     z=1: Kb = KVin_b @ Wk
//  z=2: Vt[512,M] = Wv^T . kv^T    (A=Wvt, B=KVin_b)
// NO scale folding — attn applies the 0.125 itself (known-good R5 semantics).
// ---------------------------------------------------------------------------
__global__ __launch_bounds__(256, 2) void gemm_qkv(const u16* __restrict__ Qin,
                                                   const u16* __restrict__ KVin,
                                                   const u16* __restrict__ Wqt,
                                                   const u16* __restrict__ Wkt,
                                                   const u16* __restrict__ Wvt,
                                                   u16* __restrict__ Qb,
                                                   u16* __restrict__ Kb,
                                                   u16* __restrict__ Vt) {
  __shared__ __attribute__((aligned(16))) u16 As[256 * 32];   // 16 KB
  __shared__ __attribute__((aligned(16))) u16 Bs[128 * 32];   // 8 KB
  const int tid = threadIdx.x;
  const int lane = tid & 63;
  const int w = tid >> 6;
  const int l15 = lane & 15;
  const int quad = lane >> 4;
  const int z = blockIdx.z;
  const int bid = blockIdx.x;          // 0..255
  const int wr = (w >> 1) * 128, wc = (w & 1) * 64;
  const int srow = lane >> 2;
  const int scol = (lane & 3) * 8;

  int gm, gn;
  const u16 *A, *B;
  if (z < 2) {
    gm = (bid >> 2) * 256;  gn = (bid & 3) * 128;     // 64 m-tiles x 4 n-tiles
    A = z ? KVin : Qin;  B = z ? Wkt : Wqt;
  } else {
    gm = (bid & 1) * 256;   gn = (bid >> 1) * 128;    // 2 m-tiles x 128 n-tiles
    A = Wvt; B = KVin;
  }

  f32x4 acc[8][4] = {};

  for (int k0 = 0; k0 < DIM; k0 += 32) {
    __syncthreads();
    // A: 256x32; wave w stages rows [w*64, w*64+64) -> 4 GLL16
#pragma unroll
    for (int i = 0; i < 4; i++) {
      int r0 = w * 64 + i * 16;
      GLL16(&A[(size_t)(gm + r0 + srow) * DIM + k0 + scol], &As[r0 * 32]);
    }
    // B: 128x32; wave w stages rows [w*32, w*32+32) -> 2 GLL16
#pragma unroll
    for (int i = 0; i < 2; i++) {
      int r0 = w * 32 + i * 16;
      GLL16(&B[(size_t)(gn + r0 + srow) * DIM + k0 + scol], &Bs[r0 * 32]);
    }
    __syncthreads();

    bf16x8 af[8], bfr[4];
#pragma unroll
    for (int mt = 0; mt < 8; mt++)
      af[mt] = *reinterpret_cast<const bf16x8*>(&As[(wr + mt * 16 + l15) * 32 + quad * 8]);
#pragma unroll
    for (int nt = 0; nt < 4; nt++)
      bfr[nt] = *reinterpret_cast<const bf16x8*>(&Bs[(wc + nt * 16 + l15) * 32 + quad * 8]);
#pragma unroll
    for (int mt = 0; mt < 8; mt++)
#pragma unroll
      for (int nt = 0; nt < 4; nt++)
        acc[mt][nt] = __builtin_amdgcn_mfma_f32_16x16x32_bf16(af[mt], bfr[nt], acc[mt][nt], 0, 0, 0);
  }

  if (z < 2) {
    u16* C = (z == 0) ? Qb : Kb;
#pragma unroll
    for (int mt = 0; mt < 8; mt++)
#pragma unroll
      for (int nt = 0; nt < 4; nt++)
#pragma unroll
        for (int r = 0; r < 4; r++)
          C[(size_t)(gm + wr + mt * 16 + quad * 4 + r) * DIM + gn + wc + nt * 16 + l15] = f2b(acc[mt][nt][r]);
  } else {
#pragma unroll
    for (int mt = 0; mt < 8; mt++)
#pragma unroll
      for (int nt = 0; nt < 4; nt++)
#pragma unroll
        for (int r = 0; r < 4; r++)
          Vt[(size_t)(gm + wr + mt * 16 + quad * 4 + r) * M_ROWS + gn + wc + nt * 16 + l15] = f2b(acc[mt][nt][r]);
  }
}

// ---------------------------------------------------------------------------
// Kernel 2: flash attention — R0 known-good dataflow (LDS Pq, fences, __expf)
// with ONE change: bijective XCD swizzle of blockIdx so the 4 q-tile blocks
// sharing a (bp,h) K/V panel land on the SAME XCD's L2 (they were round-robin
// split across all 8 XCDs -> every block re-fetched its panel from HBM;
// FETCH_SIZE 73.8MB vs ~32MB of K/V). 128 blocks/XCD cover 32 panels
// (~4MB K+V) ~= one XCD L2.
// ---------------------------------------------------------------------------
__global__ __launch_bounds__(256) void attn(const u16* __restrict__ Qb,
                                            const u16* __restrict__ Kb,
                                            const u16* __restrict__ Vtg,
                                            u16* __restrict__ Ob) {
  __shared__ __attribute__((aligned(16))) u16 Ks[2 * 128 * 32];   // [kd-plane][key][32]
  __shared__ __attribute__((aligned(16))) u16 Vs[4 * 64 * 32];    // [key-plane][d][32]
  __shared__ __attribute__((aligned(16))) u16 Pq[4][16 * 136];    // per-wave P [q][key]

  const int tid = threadIdx.x;
  const int lane = tid & 63;
  const int w = tid >> 6;
  const int l15 = lane & 15;
  const int quad = lane >> 4;
  const int srow = lane >> 2;
  const int scol = (lane & 3) * 8;

  // XCD swizzle: hw index d -> logical bid = (d&7)*128 + (d>>3). Bijective on
  // [0,1024). Panel group {4p..4p+3} maps to hw indices differing by 8 ->
  // same XCD under round-robin dispatch. Perf-only (any mapping is correct).
  const int d = blockIdx.x;
  const int bid = (d & 7) * 128 + (d >> 3);
  const int qt = bid & 3;            // 4 q-tiles of 128 rows
  const int bhp = bid >> 2;
  const int h = bhp & 7;
  const int bp = bhp >> 3;           // 0..31
  const int qrow0 = bp * SEQ + qt * 128;
  const int col0 = h * DHEAD;

  // Q fragments direct from global (B-operand layout: lane holds q=l15)
  bf16x8 qf[2][2];
#pragma unroll
  for (int g = 0; g < 2; g++)
#pragma unroll
    for (int kd = 0; kd < 2; kd++)
      qf[g][kd] = *reinterpret_cast<const bf16x8*>(
          &Qb[(size_t)(qrow0 + w * 32 + g * 16 + l15) * DIM + col0 + kd * 32 + quad * 8]);

  float m_[2] = {-1e30f, -1e30f}, l_[2] = {0.0f, 0.0f};
  f32x4 o[2][4] = {};

  for (int j = 0; j < 4; j++) {
    __syncthreads();
    const int krow0 = bp * SEQ + j * 128;
    // K staging: 16 GLL16 (plane=kd 0..1, chunk 0..7); wave w takes t=4w..4w+3
#pragma unroll
    for (int i = 0; i < 4; i++) {
      int t = w * 4 + i;
      int plane = t & 1, chunk = t >> 1;
      GLL16(&Kb[(size_t)(krow0 + chunk * 16 + srow) * DIM + col0 + plane * 32 + scol],
            &Ks[plane * 4096 + chunk * 512]);
    }
    // V staging: 16 GLL16 (plane=key-chunk 0..3, chunk=d-chunk 0..3)
#pragma unroll
    for (int i = 0; i < 4; i++) {
      int t = w * 4 + i;
      int plane = t & 3, chunk = t >> 2;
      GLL16(&Vtg[(size_t)(col0 + chunk * 16 + srow) * M_ROWS + krow0 + plane * 32 + scol],
            &Vs[plane * 2048 + chunk * 512]);
    }
    __syncthreads();

#pragma unroll
    for (int g = 0; g < 2; g++) {
      // S^T = K*Q^T : 8 key-tiles of 16; D[key][q=l15]
      f32x4 st[8];
#pragma unroll
      for (int ct = 0; ct < 8; ct++) {
        f32x4 z = {};
#pragma unroll
        for (int kd = 0; kd < 2; kd++) {
          bf16x8 kf = *reinterpret_cast<const bf16x8*>(&Ks[kd * 4096 + (ct * 16 + l15) * 32 + quad * 8]);
          z = __builtin_amdgcn_mfma_f32_16x16x32_bf16(kf, qf[g][kd], z, 0, 0, 0);
        }
        st[ct] = z * 0.125f;
      }

      // online softmax for q=l15 over 128 keys (32/lane, reduce across quads)
      float pm = -1e30f;
#pragma unroll
      for (int ct = 0; ct < 8; ct++)
#pragma unroll
        for (int r = 0; r < 4; r++) pm = fmaxf(pm, st[ct][r]);
      pm = fmaxf(pm, __shfl_xor(pm, 16));
      pm = fmaxf(pm, __shfl_xor(pm, 32));
      float mn = fmaxf(m_[g], pm);
      float alpha = __expf(m_[g] - mn);
      m_[g] = mn;
      float rs = 0.0f;
#pragma unroll
      for (int ct = 0; ct < 8; ct++)
#pragma unroll
        for (int r = 0; r < 4; r++) {
          float pv = __expf(st[ct][r] - mn);
          st[ct][r] = pv;
          rs += pv;
        }
      rs += __shfl_xor(rs, 16);
      rs += __shfl_xor(rs, 32);
      l_[g] = l_[g] * alpha + rs;
#pragma unroll
      for (int r = 0; r < 4; r++) {
        float ar = __shfl(alpha, quad * 4 + r);
#pragma unroll
        for (int nt = 0; nt < 4; nt++) o[g][nt][r] *= ar;
      }

      // P^T (C-layout) -> Pq[q][key], packed b64 stores
#pragma unroll
      for (int ct = 0; ct < 8; ct++) {
        u16x4 pk;
#pragma unroll
        for (int e = 0; e < 4; e++) pk[e] = f2b(st[ct][e]);
        *reinterpret_cast<u16x4*>(&Pq[w][l15 * 136 + ct * 16 + quad * 4]) = pk;
      }
      __threadfence_block();   // order Pq stores -> Pq reads

      // O += P*V : A = Pq[q=l15][key], B = Vs plane c2 [d][key-chunk]
#pragma unroll
      for (int c2 = 0; c2 < 4; c2++) {
        bf16x8 af = *reinterpret_cast<const bf16x8*>(&Pq[w][l15 * 136 + c2 * 32 + quad * 8]);
#pragma unroll
        for (int nt = 0; nt < 4; nt++) {
          bf16x8 bv = *reinterpret_cast<const bf16x8*>(&Vs[c2 * 2048 + (nt * 16 + l15) * 32 + quad * 8]);
          o[g][nt] = __builtin_amdgcn_mfma_f32_16x16x32_bf16(af, bv, o[g][nt], 0, 0, 0);
        }
      }
      __threadfence_block();   // order Pq reads -> next group's Pq stores
    }
  }

  // epilogue: normalize and write bf16 [M,512]
#pragma unroll
  for (int g = 0; g < 2; g++) {
    float inv = 1.0f / l_[g];
#pragma unroll
    for (int r = 0; r < 4; r++) {
      float lr = __shfl(inv, quad * 4 + r);
      int row = qrow0 + w * 32 + g * 16 + quad * 4 + r;
#pragma unroll
      for (int nt = 0; nt < 4; nt++)
        Ob[(size_t)row * DIM + col0 + nt * 16 + l15] = f2b(o[g][nt][r] * lr);
    }
  }
}

// ---------------------------------------------------------------------------
// Kernel 3: output GEMM, m97-style staging; fp32 epilogue + bias.
// ---------------------------------------------------------------------------
__global__ __launch_bounds__(256) void gemm_out(const u16* __restrict__ Ab,
                                                const u16* __restrict__ Bt,
                                                const float* __restrict__ bias,
                                                float* __restrict__ C) {
  __shared__ __attribute__((aligned(16))) u16 As[128 * 32];
  __shared__ __attribute__((aligned(16))) u16 Bs[128 * 32];
  const int tid = threadIdx.x;
  const int lane = tid & 63;
  const int w = tid >> 6;
  const int l15 = lane & 15;
  const int quad = lane >> 4;
  const int gm = blockIdx.y * 128;
  const int gn = blockIdx.x * 128;
  const int wr = (w >> 1) * 64, wc = (w & 1) * 64;
  const int srow = lane >> 2;
  const int scol = (lane & 3) * 8;

  f32x4 acc[4][4] = {};

  for (int k0 = 0; k0 < DIM; k0 += 32) {
    __syncthreads();
#pragma unroll
    for (int i = 0; i < 2; i++) {
      int r0 = w * 32 + i * 16;
      GLL16(&Ab[(size_t)(gm + r0 + srow) * DIM + k0 + scol], &As[r0 * 32]);
      GLL16(&Bt[(size_t)(gn + r0 + srow) * DIM + k0 + scol], &Bs[r0 * 32]);
    }
    __syncthreads();

    bf16x8 af[4], bfr[4];
#pragma unroll
    for (int mt = 0; mt < 4; mt++)
      af[mt] = *reinterpret_cast<const bf16x8*>(&As[(wr + mt * 16 + l15) * 32 + quad * 8]);
#pragma unroll
    for (int nt = 0; nt < 4; nt++)
      bfr[nt] = *reinterpret_cast<const bf16x8*>(&Bs[(wc + nt * 16 + l15) * 32 + quad * 8]);
#pragma unroll
    for (int mt = 0; mt < 4; mt++)
#pragma unroll
      for (int nt = 0; nt < 4; nt++)
        acc[mt][nt] = __builtin_amdgcn_mfma_f32_16x16x32_bf16(af[mt], bfr[nt], acc[mt][nt], 0, 0, 0);
  }

#pragma unroll
  for (int mt = 0; mt < 4; mt++)
#pragma unroll
    for (int nt = 0; nt < 4; nt++) {
      float bcol = bias[gn + wc + nt * 16 + l15];
#pragma unroll
      for (int r = 0; r < 4; r++)
        C[(size_t)(gm + wr + mt * 16 + quad * 4 + r) * DIM + gn + wc + nt * 16 + l15] = acc[mt][nt][r] + bcol;
    }
}

// ---------------------------------------------------------------------------
extern "C" void kernel_launch(void* const* d_in, const int* in_sizes, int n_in,
                              void* d_out, int out_size, void* d_ws, size_t ws_size,
                              hipStream_t stream) {
  const float* q_in  = (const float*)d_in[0];
  const float* kv_in = (const float*)d_in[1];
  const float* Wq    = (const float*)d_in[2];
  const float* Wk    = (const float*)d_in[3];
  const float* Wv    = (const float*)d_in[4];
  const float* Wo    = (const float*)d_in[5];
  const float* bo    = (const float*)d_in[6];
  float* out = (float*)d_out;

  u16* ws = (u16*)d_ws;
  u16* Wqt = ws;
  u16* Wkt = ws + 262144;
  u16* Wvt = ws + 524288;
  u16* Wot = ws + 786432;
  u16* Qb  = ws + 1048576;
  u16* Kb  = Qb + (size_t)M_ROWS * DIM;
  u16* Vtg = Kb + (size_t)M_ROWS * DIM;
  u16* Ob  = Vtg + (size_t)M_ROWS * DIM;
  // bf16 copies of the fp32 inputs live in d_out (dead before gemm_out writes it)
  u16* Qin_b  = (u16*)d_out;
  u16* KVin_b = Qin_b + (size_t)M_ROWS * DIM;

  prep<<<dim3(9216), 256, 0, stream>>>(q_in, kv_in, Wq, Wk, Wv, Wo, Qin_b, KVin_b, ws);
  gemm_qkv<<<dim3(256, 1, 3), 256, 0, stream>>>(Qin_b, KVin_b, Wqt, Wkt, Wvt, Qb, Kb, Vtg);
  attn<<<dim3(1024), 256, 0, stream>>>(Qb, Kb, Vtg, Ob);
  gemm_out<<<dim3(4, 128), 256, 0, stream>>>(Ob, Wot, bo, out);
}